// Round 9
// baseline (310.057 us; speedup 1.0000x reference)
//
#include <hip/hip_runtime.h>

#define BGR 32768
#define NNODE 19
#define NTOT (BGR*NNODE)       // 622592
#define EF 120
#define ES 60
#define NB 5
#define EPS 1e-5f

// ---- workspace layout (float offsets) ----
#define WS_U     0                          // NTOT*NB (node-major [g][v*5+b])
#define WS_PRE2  (WS_U + NTOT*NB)           // BGR*190 (node-major [g][(v*5+b)*2+kk])
#define WS_PRE3  (WS_PRE2 + BGR*190)        // BGR*128
#define WS_P3    (WS_PRE3 + BGR*128)        // 512*256
#define WS_R3    (WS_P3 + 131072)           // 64*256
#define WS_P1    (WS_R3 + 16384)            // 640*10
#define WS_R2    (WS_P1 + 6400)             // 640*20
#define WS_WP    (WS_R2 + 12800)            // 192*128 (k-major)
#define WS_TB    (WS_WP + 24576)            // 168
#define WS_TSEG  (WS_TB + 168)              // 165 float4 = 660

// ---------------- K1: dense-N GCN1 -> u (node-major). band-major LDS, b128 dense loop ----------------
__global__ __launch_bounds__(256) void k1_gcn1(
    const float* __restrict__ x, const float* __restrict__ ew,
    const int* __restrict__ srcf, const int* __restrict__ dstf,
    float* __restrict__ U)
{
    __shared__ float xgb[4][100];      // band-major [b][s], pitch 20, col19 = 0; scaled by dinv[s]
    __shared__ float Nr[4][400];       // weighted adjacency [d][s], pitch 20, col19 = 0
    __shared__ float dinv[4][20];      // dinv[19] = 0
    int t = threadIdx.x, q = t >> 6, lane = t & 63;
    int g = blockIdx.x*4 + q;

    int s0, d0, s1 = 0, d1 = 0; float w0, w1 = 0.f;
    bool e1 = (lane < EF - 64);
    s0 = srcf[g*EF+lane] - g*NNODE; d0 = dstf[g*EF+lane] - g*NNODE; w0 = ew[g*EF+lane];
    if (e1) { s1 = srcf[g*EF+lane+64] - g*NNODE; d1 = dstf[g*EF+lane+64] - g*NNODE; w1 = ew[g*EF+lane+64]; }
    for (int j = lane; j < 100; j += 64) {
        int b = j/20, s = j - 20*b;
        xgb[q][j] = (s < 19) ? x[g*95 + s*5 + b] : 0.f;
    }
    for (int i = lane; i < 400; i += 64) Nr[q][i] = 0.f;
    __syncthreads();

    atomicAdd(&Nr[q][d0*20 + s0], w0);
    if (e1) atomicAdd(&Nr[q][d1*20 + s1], w1);
    __syncthreads();

    if (lane < 20) {
        float dv = 0.f;
        if (lane < 19) {
            float s = 0.f;
            #pragma unroll
            for (int k = 0; k < 19; k++) s += Nr[q][lane*20 + k];
            dv = rsqrtf(s + 1.f);
        }
        dinv[q][lane] = dv;
    }
    __syncthreads();
    for (int j = lane; j < 100; j += 64) xgb[q][j] *= dinv[q][j % 20];
    __syncthreads();

    for (int i = lane; i < 95; i += 64) {
        int v = i/5, b = i - 5*v;
        float acc = xgb[q][b*20 + v];        // self: dinv[v]*x
        const float4* nrp = (const float4*)&Nr[q][v*20];
        const float4* xbp = (const float4*)&xgb[q][b*20];
        #pragma unroll
        for (int j = 0; j < 5; j++) {
            float4 n4 = nrp[j], x4 = xbp[j];
            acc += n4.x*x4.x + n4.y*x4.y + n4.z*x4.z + n4.w*x4.w;
        }
        U[(size_t)g*95 + i] = dinv[q][v] * acc;
    }
}

// ---------------- KR1: U stats -> P1[640][10]; blocks 0..95 also build Wp ----------------
__global__ __launch_bounds__(256) void kr1(const float* __restrict__ U, float* __restrict__ P1,
    const float* __restrict__ W, float* __restrict__ Wp)
{
    int t = threadIdx.x;
    if (blockIdx.x < 96) {
        int idx = blockIdx.x*256 + t;       // 96*256 = 192*128
        int k = idx >> 7, f = idx & 127;
        float val = 0.f;
        if (k < 190) {
            int p = k >> 1, kk = k & 1;
            int v = p/5, b = p - 5*v;
            val = W[(b*38 + v*2 + kk)*128 + f];
        }
        Wp[idx] = val;
    }
    const int CH = NTOT*NB/640;             // 4864
    size_t base = (size_t)blockIdx.x * CH;
    float s[5], qq[5];
    #pragma unroll
    for (int b = 0; b < 5; b++) { s[b] = 0.f; qq[b] = 0.f; }
    int m = (int)((base + t) % 5);
    for (int n = 0; n < CH/256; n++) {      // 19 iters
        float v = U[base + n*256 + t];
        #pragma unroll
        for (int b = 0; b < 5; b++) {
            bool hit = (m == b);
            s[b]  += hit ? v   : 0.f;
            qq[b] += hit ? v*v : 0.f;
        }
        m++; if (m == 5) m = 0;
    }
    __shared__ float red[256][10];
    #pragma unroll
    for (int b = 0; b < 5; b++) { red[t][b] = s[b]; red[t][5+b] = qq[b]; }
    __syncthreads();
    for (int off = 128; off > 0; off >>= 1) {
        if (t < off) {
            #pragma unroll
            for (int k = 0; k < 10; k++) red[t][k] += red[t+off][k];
        }
        __syncthreads();
    }
    if (t < 10) P1[blockIdx.x*10 + t] = red[0][t];
}

// ---------------- K2C: P1 -> BN1 stats -> PWL tables TB/TSEG ----------------
__global__ __launch_bounds__(256) void k2c(const float* __restrict__ P1,
    const float* __restrict__ W1, const float* __restrict__ g1, const float* __restrict__ bt1,
    const float* __restrict__ W2, float* __restrict__ TB, float4* __restrict__ TSEG)
{
    __shared__ float red[16][10];
    __shared__ float mean[5], varr[5];
    __shared__ float  traw[5][32];
    __shared__ float4 dlt[5][32];
    __shared__ float  acc0[5][4];
    int t = threadIdx.x;

    if (t < 160) {
        int col = t % 10, grp = t / 10;
        float acc = 0.f;
        for (int j = grp; j < 640; j += 16) acc += P1[j*10 + col];
        red[grp][col] = acc;
    }
    if (t < 20) ((float*)acc0)[t] = 0.f;
    __syncthreads();
    if (t < 10) {
        float ss = 0.f;
        #pragma unroll
        for (int j = 0; j < 16; j++) ss += red[j][t];
        red[0][t] = ss;
    }
    __syncthreads();
    if (t < 5) {
        float m = red[0][t] / (float)NTOT;
        mean[t] = m;
        varr[t] = red[0][5+t] / (float)NTOT - m*m;
    }
    __syncthreads();

    int b = 0, f = 0; float a = 0.f, d = 0.f, wx = 0.f, wy = 0.f, tf = 0.f; bool dg = true;
    if (t < 160) {
        b = t >> 5; f = t & 31;
        float w = W1[t];
        a = w * rsqrtf(w*w*varr[b] + EPS) * g1[t];
        d = bt1[t] - a*mean[b];
        wx = W2[t*2]; wy = W2[t*2+1];
        dg = (fabsf(a) < 1e-30f);
        tf = dg ? 3.0e38f : (-d/a);
        traw[b][f] = tf;
        if (dg) {
            float rd = fmaxf(d, 0.f);
            atomicAdd(&acc0[b][1], wx*rd);
            atomicAdd(&acc0[b][3], wy*rd);
        } else if (a < 0.f) {
            atomicAdd(&acc0[b][0], wx*a);
            atomicAdd(&acc0[b][1], wx*d);
            atomicAdd(&acc0[b][2], wy*a);
            atomicAdd(&acc0[b][3], wy*d);
        }
    }
    __syncthreads();
    if (t < 160) {
        int r = 0;
        #pragma unroll
        for (int ff = 0; ff < 32; ff++) {
            float o = traw[b][ff];
            r += (o < tf || (o == tf && ff < f)) ? 1 : 0;
        }
        TB[b*33 + r] = tf;
        float4 dl = make_float4(0.f, 0.f, 0.f, 0.f);
        if (!dg) {
            float sgn = (a > 0.f) ? 1.f : -1.f;
            dl = make_float4(sgn*wx*a, sgn*wx*d, sgn*wy*a, sgn*wy*d);
        }
        dlt[b][r] = dl;
    }
    if (t < 5) TB[t*33 + 32] = 3.0e38f;
    __syncthreads();
    if (t < 5) {
        float sx = acc0[t][0], cx = acc0[t][1], sy = acc0[t][2], cy = acc0[t][3];
        TSEG[t*33 + 0] = make_float4(sx, cx, sy, cy);
        for (int r = 0; r < 32; r++) {
            float4 dl = dlt[t][r];
            sx += dl.x; cx += dl.y; sy += dl.z; cy += dl.w;
            TSEG[t*33 + r + 1] = make_float4(sx, cx, sy, cy);
        }
    }
}

// ---------------- K3b: fused PWL-h2 + dense-M GCN2, band-major b128 dense loop ----------------
__global__ __launch_bounds__(256) void k3b(
    const float* __restrict__ U, const int* __restrict__ srcs, const int* __restrict__ dsts,
    const float* __restrict__ TBg, const float4* __restrict__ TSEGg,
    const float* __restrict__ b2, float2* __restrict__ pre2)
{
    __shared__ float  tt[168];
    __shared__ float4 tseg[165];
    __shared__ float2 h2b[4][100];     // band-major [b][s], pitch 20, scaled by dinv[s], col19=0
    __shared__ float  Mr[4][400];      // struct adjacency [d][s], pitch 20, col19=0
    __shared__ float  dinv[4][20];
    __shared__ float  b2l[12];
    int t = threadIdx.x, q = t >> 6, lane = t & 63;
    int g = blockIdx.x*4 + q;

    if (t < 165) { tt[t] = TBg[t]; tseg[t] = TSEGg[t]; }
    float u0 = U[(size_t)g*95 + lane];
    float u1 = (lane < 31) ? U[(size_t)g*95 + lane + 64] : 0.f;
    int ls = 0, ld = 0; bool ee = (lane < ES);
    if (ee) { ls = srcs[g*ES+lane] - g*NNODE; ld = dsts[g*ES+lane] - g*NNODE; }
    if (t < 10) b2l[t] = b2[t];
    for (int i = lane; i < 400; i += 64) Mr[q][i] = 0.f;
    __syncthreads();

    if (ee) atomicAdd(&Mr[q][ld*20 + ls], 1.f);
    __syncthreads();

    if (lane < 20) {
        float dv = 0.f;
        if (lane < 19) {
            float s = 0.f;
            #pragma unroll
            for (int k = 0; k < 19; k++) s += Mr[q][lane*20 + k];
            dv = rsqrtf(s + 1.f);
        }
        dinv[q][lane] = dv;
    }
    __syncthreads();

    {
        int v0 = lane/5, b0 = lane - 5*v0;
        int j = 0;
        #pragma unroll
        for (int st = 32; st > 0; st >>= 1) {
            int nx = j + st;
            if (nx <= 32 && u0 >= tt[b0*33 + nx - 1]) j = nx;
        }
        float4 sc = tseg[b0*33 + j];
        float dv = dinv[q][v0];
        h2b[q][b0*20 + v0] = make_float2(dv*fmaf(sc.x, u0, sc.y), dv*fmaf(sc.z, u0, sc.w));
        if (lane < 31) {
            int i1 = lane + 64, v1 = i1/5, b1 = i1 - 5*v1;
            int j1 = 0;
            #pragma unroll
            for (int st = 32; st > 0; st >>= 1) {
                int nx = j1 + st;
                if (nx <= 32 && u1 >= tt[b1*33 + nx - 1]) j1 = nx;
            }
            float4 sc1 = tseg[b1*33 + j1];
            float dv1 = dinv[q][v1];
            h2b[q][b1*20 + v1] = make_float2(dv1*fmaf(sc1.x, u1, sc1.y), dv1*fmaf(sc1.z, u1, sc1.w));
        }
        if (lane < 5) h2b[q][lane*20 + 19] = make_float2(0.f, 0.f);
    }
    __syncthreads();

    for (int i = lane; i < 95; i += 64) {
        int v = i/5, b = i - 5*v;
        float2 self = h2b[q][b*20 + v];
        float ax = self.x, ay = self.y;
        const float4* mp = (const float4*)&Mr[q][v*20];
        const float4* hp = (const float4*)&h2b[q][b*20];
        #pragma unroll
        for (int j = 0; j < 5; j++) {
            float4 m4 = mp[j];
            float4 hA = hp[2*j], hB = hp[2*j+1];
            ax += m4.x*hA.x + m4.y*hA.z + m4.z*hB.x + m4.w*hB.z;
            ay += m4.x*hA.y + m4.y*hA.w + m4.z*hB.y + m4.w*hB.w;
        }
        float dv = dinv[q][v];
        pre2[(size_t)g*95 + i] = make_float2(fmaf(dv, ax, b2l[2*b]),
                                             fmaf(dv, ay, b2l[2*b+1]));
    }
}

// ---------------- KR2: per-(b,k) sum & sumsq over PRE2, 640 blocks ----------------
__global__ __launch_bounds__(256) void kr2(const float2* __restrict__ pre2, float* __restrict__ r2)
{
    int t = threadIdx.x;
    size_t base = (size_t)blockIdx.x * 4864;          // 640*4864 = BGR*95
    float sx[5], sy[5], qx[5], qy[5];
    #pragma unroll
    for (int b = 0; b < 5; b++) { sx[b]=0.f; sy[b]=0.f; qx[b]=0.f; qy[b]=0.f; }
    for (int n = 0; n < 19; n++) {
        size_t i = base + n*256 + t;
        float2 v = pre2[i];
        int p = (int)(i % 95);
        int b = p % 5;
        #pragma unroll
        for (int bb = 0; bb < 5; bb++) {
            bool m = (b == bb);
            sx[bb] += m ? v.x : 0.f;     sy[bb] += m ? v.y : 0.f;
            qx[bb] += m ? v.x*v.x : 0.f; qy[bb] += m ? v.y*v.y : 0.f;
        }
    }
    __shared__ float red[256][20];
    #pragma unroll
    for (int b = 0; b < 5; b++) {
        red[t][2*b] = sx[b];      red[t][2*b+1] = sy[b];
        red[t][10+2*b] = qx[b];   red[t][11+2*b] = qy[b];
    }
    __syncthreads();
    for (int off = 128; off > 0; off >>= 1) {
        if (t < off) {
            #pragma unroll
            for (int k = 0; k < 20; k++) red[t][k] += red[t+off][k];
        }
        __syncthreads();
    }
    if (t < 20) r2[blockIdx.x*20 + t] = red[0][t];
}

// ---------------- K5: BN2-finalize + relu(BN2(pre2)) @ Wp + b. 64 graphs/block ----------------
__global__ __launch_bounds__(256) void k5_lin1(
    const float2* __restrict__ pre2, const float* __restrict__ R2,
    const float* __restrict__ g2, const float* __restrict__ bt2,
    const float* __restrict__ Wp, const float* __restrict__ bias,
    float* __restrict__ pre3, float* __restrict__ p3)
{
    __shared__ float xg[64*192];       // 49.2 KB, k-padded to 192
    __shared__ float a2l[10], d2l[10];
    __shared__ float r20[12][20];
    __shared__ float redS[8][128], redQ[8][128];
    int t = threadIdx.x, bid = blockIdx.x;

    if (t < 240) {                      // BN2 finalize from R2[640][20]
        int col = t % 20, grp = t / 20;
        float s = 0.f;
        for (int j = grp; j < 640; j += 12) s += R2[j*20 + col];
        r20[grp][col] = s;
    }
    if (t < 128) xg[(t >> 1)*192 + 190 + (t & 1)] = 0.f;   // zero k-pad (64 rows x 2)
    __syncthreads();
    if (t < 20) {
        float s = 0.f;
        #pragma unroll
        for (int j = 0; j < 12; j++) s += r20[j][t];
        r20[0][t] = s;
    }
    __syncthreads();
    if (t < 10) {
        float m = r20[0][t] / (float)NTOT;
        float v = r20[0][10+t] / (float)NTOT - m*m;
        float a = g2[t] * rsqrtf(v + EPS);
        a2l[t] = a;
        d2l[t] = bt2[t] - a*m;
    }
    __syncthreads();

    const float2* src = pre2 + (size_t)bid*6080;      // 64 graphs * 95 float2
    for (int i = t; i < 6080; i += 256) {
        int gg = i / 95, p = i - gg*95;
        int b = p % 5;
        float2 v = src[i];
        xg[gg*192 + 2*p]     = fmaxf(fmaf(a2l[2*b],   v.x, d2l[2*b]),   0.f);
        xg[gg*192 + 2*p + 1] = fmaxf(fmaf(a2l[2*b+1], v.y, d2l[2*b+1]), 0.f);
    }
    __syncthreads();

    int lane = t & 63, h = t >> 6;
    int f32 = lane & 31, gh = lane >> 5;       // half-wave owns 8 graphs; lane feats 4f32..+3
    const float* xh = xg + (h*16 + gh*8)*192;
    float acc[8][4];
    #pragma unroll
    for (int r = 0; r < 8; r++)
        #pragma unroll
        for (int c = 0; c < 4; c++) acc[r][c] = 0.f;

    for (int kt = 0; kt < 24; kt++) {
        float4 w[8];
        #pragma unroll
        for (int j = 0; j < 8; j++)
            w[j] = *(const float4*)(Wp + (kt*8 + j)*128 + 4*f32);   // coalesced 512B
        #pragma unroll
        for (int r = 0; r < 8; r++) {
            float4 xa = *(const float4*)(xh + r*192 + kt*8);
            float4 xb = *(const float4*)(xh + r*192 + kt*8 + 4);
            #pragma unroll
            for (int c = 0; c < 4; c++) {
                float a = acc[r][c];
                a = fmaf(xa.x, ((const float*)&w[0])[c], a);
                a = fmaf(xa.y, ((const float*)&w[1])[c], a);
                a = fmaf(xa.z, ((const float*)&w[2])[c], a);
                a = fmaf(xa.w, ((const float*)&w[3])[c], a);
                a = fmaf(xb.x, ((const float*)&w[4])[c], a);
                a = fmaf(xb.y, ((const float*)&w[5])[c], a);
                a = fmaf(xb.z, ((const float*)&w[6])[c], a);
                a = fmaf(xb.w, ((const float*)&w[7])[c], a);
                acc[r][c] = a;
            }
        }
    }

    int gbase = bid*64 + h*16 + gh*8;
    float4 b4 = *(const float4*)(bias + 4*f32);
    float s4[4] = {0.f,0.f,0.f,0.f}, q4[4] = {0.f,0.f,0.f,0.f};
    #pragma unroll
    for (int r = 0; r < 8; r++) {
        float4 pv;
        pv.x = acc[r][0] + b4.x;
        pv.y = acc[r][1] + b4.y;
        pv.z = acc[r][2] + b4.z;
        pv.w = acc[r][3] + b4.w;
        *(float4*)(pre3 + (size_t)(gbase + r)*128 + 4*f32) = pv;
        s4[0]+=pv.x; s4[1]+=pv.y; s4[2]+=pv.z; s4[3]+=pv.w;
        q4[0]+=pv.x*pv.x; q4[1]+=pv.y*pv.y; q4[2]+=pv.z*pv.z; q4[3]+=pv.w*pv.w;
    }
    *(float4*)&redS[h*2 + gh][4*f32] = make_float4(s4[0], s4[1], s4[2], s4[3]);
    *(float4*)&redQ[h*2 + gh][4*f32] = make_float4(q4[0], q4[1], q4[2], q4[3]);
    __syncthreads();
    if (t < 128) {
        float s = 0.f;
        #pragma unroll
        for (int j = 0; j < 8; j++) s += redS[j][t];
        p3[bid*256 + t] = s;
    } else {
        int f = t - 128;
        float qq = 0.f;
        #pragma unroll
        for (int j = 0; j < 8; j++) qq += redQ[j][f];
        p3[bid*256 + 128 + f] = qq;
    }
}

// ---------------- K6a: BN3 partial reduction (P3 has 512 rows) ----------------
__global__ __launch_bounds__(256) void k6a(const float* __restrict__ p3, float* __restrict__ r3)
{
    int j = blockIdx.x, f = threadIdx.x;
    float s = 0.f;
    for (int r = j*8; r < (j+1)*8; r++) s += p3[r*256 + f];
    r3[j*256 + f] = s;
}

// ---------------- K7: BN3-finalize + head. 2 threads per graph ----------------
__global__ __launch_bounds__(256) void k7_head(
    const float* __restrict__ pre3, const float* __restrict__ R3,
    const float* __restrict__ g3, const float* __restrict__ bt3,
    const float* __restrict__ W2h, const float* __restrict__ b2h,
    const float* __restrict__ W3h, const float* __restrict__ b3h,
    float* __restrict__ out)
{
    __shared__ float A3s[128], D3s[128];
    int t = threadIdx.x;
    if (t < 128) {
        float s = 0.f, q = 0.f;
        for (int j = 0; j < 64; j++) { s += R3[j*256 + t]; q += R3[j*256 + 128 + t]; }
        float m = s / (float)BGR;
        float v = q / (float)BGR - m*m;
        float a = g3[t] * rsqrtf(v + EPS);
        A3s[t] = a;
        D3s[t] = bt3[t] - a*m;
    }
    __syncthreads();

    int gi = t >> 1, half = t & 1;
    int g = blockIdx.x*128 + gi;
    const float* p3 = pre3 + (size_t)g*128 + half*64;
    const float* A3h = A3s + half*64;
    const float* D3h = D3s + half*64;
    float accj[32];
    #pragma unroll
    for (int j = 0; j < 32; j++) accj[j] = half ? 0.f : b2h[j];
    #pragma unroll 2
    for (int f4 = 0; f4 < 64; f4 += 4) {
        float4 pv = *(const float4*)(p3 + f4);
        float y0 = fmaxf(fmaf(A3h[f4+0], pv.x, D3h[f4+0]), 0.f);
        float y1 = fmaxf(fmaf(A3h[f4+1], pv.y, D3h[f4+1]), 0.f);
        float y2 = fmaxf(fmaf(A3h[f4+2], pv.z, D3h[f4+2]), 0.f);
        float y3 = fmaxf(fmaf(A3h[f4+3], pv.w, D3h[f4+3]), 0.f);
        const float* w = W2h + (half*64 + f4)*32;
        #pragma unroll
        for (int j = 0; j < 32; j++) {
            accj[j] = fmaf(y0, w[j],      accj[j]);
            accj[j] = fmaf(y1, w[32+j],   accj[j]);
            accj[j] = fmaf(y2, w[64+j],   accj[j]);
            accj[j] = fmaf(y3, w[96+j],   accj[j]);
        }
    }
    #pragma unroll
    for (int j = 0; j < 32; j++) accj[j] += __shfl_xor(accj[j], 1);
    float o0 = half ? 0.f : b3h[0];
    float o1 = half ? 0.f : b3h[1];
    int j0 = half*16;
    #pragma unroll
    for (int j = 0; j < 16; j++) {
        float yj = fmaxf(accj[j0 + j], 0.f);
        o0 = fmaf(yj, W3h[(j0+j)*2+0], o0);
        o1 = fmaf(yj, W3h[(j0+j)*2+1], o1);
    }
    o0 += __shfl_xor(o0, 1);
    o1 += __shfl_xor(o1, 1);
    if (!half) ((float2*)out)[g] = make_float2(o0, o1);
}

extern "C" void kernel_launch(void* const* d_in, const int* in_sizes, int n_in,
                              void* d_out, int out_size, void* d_ws, size_t ws_size,
                              hipStream_t stream)
{
    (void)in_sizes; (void)n_in; (void)out_size; (void)ws_size;
    const float* x    = (const float*)d_in[0];
    const float* ew   = (const float*)d_in[1];
    const int*   eif  = (const int*)d_in[2];
    const int*   eis  = (const int*)d_in[3];
    const float* W1   = (const float*)d_in[4];
    // d_in[5] = b1: cancels exactly inside BN1 (mean subtraction) — unused
    const float* g1   = (const float*)d_in[6];
    const float* bt1  = (const float*)d_in[7];
    const float* W2   = (const float*)d_in[8];
    const float* b2   = (const float*)d_in[9];
    const float* g2   = (const float*)d_in[10];
    const float* bt2  = (const float*)d_in[11];
    const float* l1W  = (const float*)d_in[12];
    const float* l1b  = (const float*)d_in[13];
    const float* g3   = (const float*)d_in[14];
    const float* bt3  = (const float*)d_in[15];
    const float* l2W  = (const float*)d_in[16];
    const float* l2b  = (const float*)d_in[17];
    const float* l3W  = (const float*)d_in[18];
    const float* l3b  = (const float*)d_in[19];
    float* out = (float*)d_out;
    float* ws  = (float*)d_ws;

    const int* srcf = eif;  const int* dstf = eif + BGR*EF;
    const int* srcs = eis;  const int* dsts = eis + BGR*ES;

    float* U    = ws + WS_U;
    float* PRE2 = ws + WS_PRE2;
    float* PRE3 = ws + WS_PRE3;
    float* P3   = ws + WS_P3;
    float* R3   = ws + WS_R3;
    float* P1   = ws + WS_P1;
    float* R2   = ws + WS_R2;
    float* WP   = ws + WS_WP;
    float* TB   = ws + WS_TB;
    float4* TSEG= (float4*)(ws + WS_TSEG);

    k1_gcn1<<<BGR/4, 256, 0, stream>>>(x, ew, srcf, dstf, U);
    kr1<<<640, 256, 0, stream>>>(U, P1, l1W, WP);
    k2c<<<1, 256, 0, stream>>>(P1, W1, g1, bt1, W2, TB, TSEG);
    k3b<<<BGR/4, 256, 0, stream>>>(U, srcs, dsts, TB, TSEG, b2, (float2*)PRE2);
    kr2<<<640, 256, 0, stream>>>((const float2*)PRE2, R2);
    k5_lin1<<<512, 256, 0, stream>>>((const float2*)PRE2, R2, g2, bt2, WP, l1b, PRE3, P3);
    k6a<<<64, 256, 0, stream>>>(P3, R3);
    k7_head<<<256, 256, 0, stream>>>(PRE3, R3, g3, bt3, l2W, l2b, l3W, l3b, out);
}

// Round 10
// 292.225 us; speedup vs baseline: 1.0610x; 1.0610x over previous
//
#include <hip/hip_runtime.h>

#define BGR 32768
#define NNODE 19
#define NTOT (BGR*NNODE)       // 622592
#define EF 120
#define ES 60
#define NB 5
#define EPS 1e-5f

// ---- workspace layout (float offsets) ----
#define WS_U     0                          // NTOT*NB (node-major [g][v*5+b])
#define WS_PRE2  (WS_U + NTOT*NB)           // BGR*190 (node-major [g][(v*5+b)*2+kk])
#define WS_PRE3  (WS_PRE2 + BGR*190)        // BGR*128
#define WS_P3    (WS_PRE3 + BGR*128)        // 512*256
#define WS_R3    (WS_P3 + 131072)           // 64*256
#define WS_P1    (WS_R3 + 16384)            // 640*10
#define WS_R2    (WS_P1 + 6400)             // 640*20
#define WS_WP    (WS_R2 + 12800)            // 192*128 (k-major)
#define WS_TB    (WS_WP + 24576)            // 168
#define WS_TSEG  (WS_TB + 168)              // 165 float4 = 660

// ---------------- K1: dense-N GCN1 -> u (node-major). band-major LDS, b128 dense loop ----------------
__global__ __launch_bounds__(256) void k1_gcn1(
    const float* __restrict__ x, const float* __restrict__ ew,
    const int* __restrict__ srcf, const int* __restrict__ dstf,
    float* __restrict__ U)
{
    __shared__ float xgb[4][100];      // band-major [b][s], pitch 20, col19 = 0; scaled by dinv[s]
    __shared__ float Nr[4][400];       // weighted adjacency [d][s], pitch 20, col19 = 0
    __shared__ float dinv[4][20];      // dinv[19] = 0
    int t = threadIdx.x, q = t >> 6, lane = t & 63;
    int g = blockIdx.x*4 + q;

    int s0, d0, s1 = 0, d1 = 0; float w0, w1 = 0.f;
    bool e1 = (lane < EF - 64);
    s0 = srcf[g*EF+lane] - g*NNODE; d0 = dstf[g*EF+lane] - g*NNODE; w0 = ew[g*EF+lane];
    if (e1) { s1 = srcf[g*EF+lane+64] - g*NNODE; d1 = dstf[g*EF+lane+64] - g*NNODE; w1 = ew[g*EF+lane+64]; }
    for (int j = lane; j < 100; j += 64) {
        int b = j/20, s = j - 20*b;
        xgb[q][j] = (s < 19) ? x[g*95 + s*5 + b] : 0.f;
    }
    for (int i = lane; i < 400; i += 64) Nr[q][i] = 0.f;
    __syncthreads();

    atomicAdd(&Nr[q][d0*20 + s0], w0);
    if (e1) atomicAdd(&Nr[q][d1*20 + s1], w1);
    __syncthreads();

    if (lane < 20) {
        float dv = 0.f;
        if (lane < 19) {
            float s = 0.f;
            #pragma unroll
            for (int k = 0; k < 19; k++) s += Nr[q][lane*20 + k];
            dv = rsqrtf(s + 1.f);
        }
        dinv[q][lane] = dv;
    }
    __syncthreads();
    for (int j = lane; j < 100; j += 64) xgb[q][j] *= dinv[q][j % 20];
    __syncthreads();

    for (int i = lane; i < 95; i += 64) {
        int v = i/5, b = i - 5*v;
        float acc = xgb[q][b*20 + v];        // self: dinv[v]*x
        const float4* nrp = (const float4*)&Nr[q][v*20];
        const float4* xbp = (const float4*)&xgb[q][b*20];
        #pragma unroll
        for (int j = 0; j < 5; j++) {
            float4 n4 = nrp[j], x4 = xbp[j];
            acc += n4.x*x4.x + n4.y*x4.y + n4.z*x4.z + n4.w*x4.w;
        }
        U[(size_t)g*95 + i] = dinv[q][v] * acc;
    }
}

// ---------------- KR1: U stats -> P1[640][10]; blocks 0..95 also build Wp ----------------
__global__ __launch_bounds__(256) void kr1(const float* __restrict__ U, float* __restrict__ P1,
    const float* __restrict__ W, float* __restrict__ Wp)
{
    int t = threadIdx.x;
    if (blockIdx.x < 96) {
        int idx = blockIdx.x*256 + t;       // 96*256 = 192*128
        int k = idx >> 7, f = idx & 127;
        float val = 0.f;
        if (k < 190) {
            int p = k >> 1, kk = k & 1;
            int v = p/5, b = p - 5*v;
            val = W[(b*38 + v*2 + kk)*128 + f];
        }
        Wp[idx] = val;
    }
    const int CH = NTOT*NB/640;             // 4864
    size_t base = (size_t)blockIdx.x * CH;
    float s[5], qq[5];
    #pragma unroll
    for (int b = 0; b < 5; b++) { s[b] = 0.f; qq[b] = 0.f; }
    int m = (int)((base + t) % 5);
    for (int n = 0; n < CH/256; n++) {      // 19 iters
        float v = U[base + n*256 + t];
        #pragma unroll
        for (int b = 0; b < 5; b++) {
            bool hit = (m == b);
            s[b]  += hit ? v   : 0.f;
            qq[b] += hit ? v*v : 0.f;
        }
        m++; if (m == 5) m = 0;
    }
    __shared__ float red[256][10];
    #pragma unroll
    for (int b = 0; b < 5; b++) { red[t][b] = s[b]; red[t][5+b] = qq[b]; }
    __syncthreads();
    for (int off = 128; off > 0; off >>= 1) {
        if (t < off) {
            #pragma unroll
            for (int k = 0; k < 10; k++) red[t][k] += red[t+off][k];
        }
        __syncthreads();
    }
    if (t < 10) P1[blockIdx.x*10 + t] = red[0][t];
}

// ---------------- K2C: P1 -> BN1 stats -> PWL tables TB/TSEG ----------------
__global__ __launch_bounds__(256) void k2c(const float* __restrict__ P1,
    const float* __restrict__ W1, const float* __restrict__ g1, const float* __restrict__ bt1,
    const float* __restrict__ W2, float* __restrict__ TB, float4* __restrict__ TSEG)
{
    __shared__ float red[16][10];
    __shared__ float mean[5], varr[5];
    __shared__ float  traw[5][32];
    __shared__ float4 dlt[5][32];
    __shared__ float  acc0[5][4];
    int t = threadIdx.x;

    if (t < 160) {
        int col = t % 10, grp = t / 10;
        float acc = 0.f;
        for (int j = grp; j < 640; j += 16) acc += P1[j*10 + col];
        red[grp][col] = acc;
    }
    if (t < 20) ((float*)acc0)[t] = 0.f;
    __syncthreads();
    if (t < 10) {
        float ss = 0.f;
        #pragma unroll
        for (int j = 0; j < 16; j++) ss += red[j][t];
        red[0][t] = ss;
    }
    __syncthreads();
    if (t < 5) {
        float m = red[0][t] / (float)NTOT;
        mean[t] = m;
        varr[t] = red[0][5+t] / (float)NTOT - m*m;
    }
    __syncthreads();

    int b = 0, f = 0; float a = 0.f, d = 0.f, wx = 0.f, wy = 0.f, tf = 0.f; bool dg = true;
    if (t < 160) {
        b = t >> 5; f = t & 31;
        float w = W1[t];
        a = w * rsqrtf(w*w*varr[b] + EPS) * g1[t];
        d = bt1[t] - a*mean[b];
        wx = W2[t*2]; wy = W2[t*2+1];
        dg = (fabsf(a) < 1e-30f);
        tf = dg ? 3.0e38f : (-d/a);
        traw[b][f] = tf;
        if (dg) {
            float rd = fmaxf(d, 0.f);
            atomicAdd(&acc0[b][1], wx*rd);
            atomicAdd(&acc0[b][3], wy*rd);
        } else if (a < 0.f) {
            atomicAdd(&acc0[b][0], wx*a);
            atomicAdd(&acc0[b][1], wx*d);
            atomicAdd(&acc0[b][2], wy*a);
            atomicAdd(&acc0[b][3], wy*d);
        }
    }
    __syncthreads();
    if (t < 160) {
        int r = 0;
        #pragma unroll
        for (int ff = 0; ff < 32; ff++) {
            float o = traw[b][ff];
            r += (o < tf || (o == tf && ff < f)) ? 1 : 0;
        }
        TB[b*33 + r] = tf;
        float4 dl = make_float4(0.f, 0.f, 0.f, 0.f);
        if (!dg) {
            float sgn = (a > 0.f) ? 1.f : -1.f;
            dl = make_float4(sgn*wx*a, sgn*wx*d, sgn*wy*a, sgn*wy*d);
        }
        dlt[b][r] = dl;
    }
    if (t < 5) TB[t*33 + 32] = 3.0e38f;
    __syncthreads();
    if (t < 5) {
        float sx = acc0[t][0], cx = acc0[t][1], sy = acc0[t][2], cy = acc0[t][3];
        TSEG[t*33 + 0] = make_float4(sx, cx, sy, cy);
        for (int r = 0; r < 32; r++) {
            float4 dl = dlt[t][r];
            sx += dl.x; cx += dl.y; sy += dl.z; cy += dl.w;
            TSEG[t*33 + r + 1] = make_float4(sx, cx, sy, cy);
        }
    }
}

// ---------------- K3b: fused PWL-h2 + dense-M GCN2, band-major b128 dense loop ----------------
__global__ __launch_bounds__(256) void k3b(
    const float* __restrict__ U, const int* __restrict__ srcs, const int* __restrict__ dsts,
    const float* __restrict__ TBg, const float4* __restrict__ TSEGg,
    const float* __restrict__ b2, float2* __restrict__ pre2)
{
    __shared__ float  tt[168];
    __shared__ float4 tseg[165];
    __shared__ float2 h2b[4][100];     // band-major [b][s], pitch 20, scaled by dinv[s], col19=0
    __shared__ float  Mr[4][400];      // struct adjacency [d][s], pitch 20, col19=0
    __shared__ float  dinv[4][20];
    __shared__ float  b2l[12];
    int t = threadIdx.x, q = t >> 6, lane = t & 63;
    int g = blockIdx.x*4 + q;

    if (t < 165) { tt[t] = TBg[t]; tseg[t] = TSEGg[t]; }
    float u0 = U[(size_t)g*95 + lane];
    float u1 = (lane < 31) ? U[(size_t)g*95 + lane + 64] : 0.f;
    int ls = 0, ld = 0; bool ee = (lane < ES);
    if (ee) { ls = srcs[g*ES+lane] - g*NNODE; ld = dsts[g*ES+lane] - g*NNODE; }
    if (t < 10) b2l[t] = b2[t];
    for (int i = lane; i < 400; i += 64) Mr[q][i] = 0.f;
    __syncthreads();

    if (ee) atomicAdd(&Mr[q][ld*20 + ls], 1.f);
    __syncthreads();

    if (lane < 20) {
        float dv = 0.f;
        if (lane < 19) {
            float s = 0.f;
            #pragma unroll
            for (int k = 0; k < 19; k++) s += Mr[q][lane*20 + k];
            dv = rsqrtf(s + 1.f);
        }
        dinv[q][lane] = dv;
    }
    __syncthreads();

    {
        int v0 = lane/5, b0 = lane - 5*v0;
        int j = 0;
        #pragma unroll
        for (int st = 32; st > 0; st >>= 1) {
            int nx = j + st;
            if (nx <= 32 && u0 >= tt[b0*33 + nx - 1]) j = nx;
        }
        float4 sc = tseg[b0*33 + j];
        float dv = dinv[q][v0];
        h2b[q][b0*20 + v0] = make_float2(dv*fmaf(sc.x, u0, sc.y), dv*fmaf(sc.z, u0, sc.w));
        if (lane < 31) {
            int i1 = lane + 64, v1 = i1/5, b1 = i1 - 5*v1;
            int j1 = 0;
            #pragma unroll
            for (int st = 32; st > 0; st >>= 1) {
                int nx = j1 + st;
                if (nx <= 32 && u1 >= tt[b1*33 + nx - 1]) j1 = nx;
            }
            float4 sc1 = tseg[b1*33 + j1];
            float dv1 = dinv[q][v1];
            h2b[q][b1*20 + v1] = make_float2(dv1*fmaf(sc1.x, u1, sc1.y), dv1*fmaf(sc1.z, u1, sc1.w));
        }
        if (lane < 5) h2b[q][lane*20 + 19] = make_float2(0.f, 0.f);
    }
    __syncthreads();

    for (int i = lane; i < 95; i += 64) {
        int v = i/5, b = i - 5*v;
        float2 self = h2b[q][b*20 + v];
        float ax = self.x, ay = self.y;
        const float4* mp = (const float4*)&Mr[q][v*20];
        const float4* hp = (const float4*)&h2b[q][b*20];
        #pragma unroll
        for (int j = 0; j < 5; j++) {
            float4 m4 = mp[j];
            float4 hA = hp[2*j], hB = hp[2*j+1];
            ax += m4.x*hA.x + m4.y*hA.z + m4.z*hB.x + m4.w*hB.z;
            ay += m4.x*hA.y + m4.y*hA.w + m4.z*hB.y + m4.w*hB.w;
        }
        float dv = dinv[q][v];
        pre2[(size_t)g*95 + i] = make_float2(fmaf(dv, ax, b2l[2*b]),
                                             fmaf(dv, ay, b2l[2*b+1]));
    }
}

// ---------------- KR2: per-(b,k) sum & sumsq over PRE2, 640 blocks ----------------
__global__ __launch_bounds__(256) void kr2(const float2* __restrict__ pre2, float* __restrict__ r2)
{
    int t = threadIdx.x;
    size_t base = (size_t)blockIdx.x * 4864;          // 640*4864 = BGR*95
    float sx[5], sy[5], qx[5], qy[5];
    #pragma unroll
    for (int b = 0; b < 5; b++) { sx[b]=0.f; sy[b]=0.f; qx[b]=0.f; qy[b]=0.f; }
    for (int n = 0; n < 19; n++) {
        size_t i = base + n*256 + t;
        float2 v = pre2[i];
        int p = (int)(i % 95);
        int b = p % 5;
        #pragma unroll
        for (int bb = 0; bb < 5; bb++) {
            bool m = (b == bb);
            sx[bb] += m ? v.x : 0.f;     sy[bb] += m ? v.y : 0.f;
            qx[bb] += m ? v.x*v.x : 0.f; qy[bb] += m ? v.y*v.y : 0.f;
        }
    }
    __shared__ float red[256][20];
    #pragma unroll
    for (int b = 0; b < 5; b++) {
        red[t][2*b] = sx[b];      red[t][2*b+1] = sy[b];
        red[t][10+2*b] = qx[b];   red[t][11+2*b] = qy[b];
    }
    __syncthreads();
    for (int off = 128; off > 0; off >>= 1) {
        if (t < off) {
            #pragma unroll
            for (int k = 0; k < 20; k++) red[t][k] += red[t+off][k];
        }
        __syncthreads();
    }
    if (t < 20) r2[blockIdx.x*20 + t] = red[0][t];
}

// ---------------- K5: BN2-finalize + relu(BN2(pre2)) @ Wp + b. 64 graphs/block ----------------
__global__ __launch_bounds__(256) void k5_lin1(
    const float2* __restrict__ pre2, const float* __restrict__ R2,
    const float* __restrict__ g2, const float* __restrict__ bt2,
    const float* __restrict__ Wp, const float* __restrict__ bias,
    float* __restrict__ pre3, float* __restrict__ p3)
{
    __shared__ float xg[64*192];       // 49.2 KB, k-padded to 192
    __shared__ float a2l[10], d2l[10];
    __shared__ float r20[12][20];
    __shared__ float redS[8][128], redQ[8][128];
    int t = threadIdx.x, bid = blockIdx.x;

    if (t < 240) {                      // BN2 finalize from R2[640][20]
        int col = t % 20, grp = t / 20;
        float s = 0.f;
        for (int j = grp; j < 640; j += 12) s += R2[j*20 + col];
        r20[grp][col] = s;
    }
    if (t < 128) xg[(t >> 1)*192 + 190 + (t & 1)] = 0.f;   // zero k-pad (64 rows x 2)
    __syncthreads();
    if (t < 20) {
        float s = 0.f;
        #pragma unroll
        for (int j = 0; j < 12; j++) s += r20[j][t];
        r20[0][t] = s;
    }
    __syncthreads();
    if (t < 10) {
        float m = r20[0][t] / (float)NTOT;
        float v = r20[0][10+t] / (float)NTOT - m*m;
        float a = g2[t] * rsqrtf(v + EPS);
        a2l[t] = a;
        d2l[t] = bt2[t] - a*m;
    }
    __syncthreads();

    const float2* src = pre2 + (size_t)bid*6080;      // 64 graphs * 95 float2
    for (int i = t; i < 6080; i += 256) {
        int gg = i / 95, p = i - gg*95;
        int b = p % 5;
        float2 v = src[i];
        xg[gg*192 + 2*p]     = fmaxf(fmaf(a2l[2*b],   v.x, d2l[2*b]),   0.f);
        xg[gg*192 + 2*p + 1] = fmaxf(fmaf(a2l[2*b+1], v.y, d2l[2*b+1]), 0.f);
    }
    __syncthreads();

    int lane = t & 63, h = t >> 6;
    int f32 = lane & 31, gh = lane >> 5;       // half-wave owns 8 graphs; lane feats 4f32..+3
    const float* xh = xg + (h*16 + gh*8)*192;
    float acc[8][4];
    #pragma unroll
    for (int r = 0; r < 8; r++)
        #pragma unroll
        for (int c = 0; c < 4; c++) acc[r][c] = 0.f;

    for (int kt = 0; kt < 24; kt++) {
        float4 w[8];
        #pragma unroll
        for (int j = 0; j < 8; j++)
            w[j] = *(const float4*)(Wp + (kt*8 + j)*128 + 4*f32);   // coalesced 512B
        #pragma unroll
        for (int r = 0; r < 8; r++) {
            float4 xa = *(const float4*)(xh + r*192 + kt*8);
            float4 xb = *(const float4*)(xh + r*192 + kt*8 + 4);
            #pragma unroll
            for (int c = 0; c < 4; c++) {
                float a = acc[r][c];
                a = fmaf(xa.x, ((const float*)&w[0])[c], a);
                a = fmaf(xa.y, ((const float*)&w[1])[c], a);
                a = fmaf(xa.z, ((const float*)&w[2])[c], a);
                a = fmaf(xa.w, ((const float*)&w[3])[c], a);
                a = fmaf(xb.x, ((const float*)&w[4])[c], a);
                a = fmaf(xb.y, ((const float*)&w[5])[c], a);
                a = fmaf(xb.z, ((const float*)&w[6])[c], a);
                a = fmaf(xb.w, ((const float*)&w[7])[c], a);
                acc[r][c] = a;
            }
        }
    }

    int gbase = bid*64 + h*16 + gh*8;
    float4 b4 = *(const float4*)(bias + 4*f32);
    float s4[4] = {0.f,0.f,0.f,0.f}, q4[4] = {0.f,0.f,0.f,0.f};
    #pragma unroll
    for (int r = 0; r < 8; r++) {
        float4 pv;
        pv.x = acc[r][0] + b4.x;
        pv.y = acc[r][1] + b4.y;
        pv.z = acc[r][2] + b4.z;
        pv.w = acc[r][3] + b4.w;
        *(float4*)(pre3 + (size_t)(gbase + r)*128 + 4*f32) = pv;
        s4[0]+=pv.x; s4[1]+=pv.y; s4[2]+=pv.z; s4[3]+=pv.w;
        q4[0]+=pv.x*pv.x; q4[1]+=pv.y*pv.y; q4[2]+=pv.z*pv.z; q4[3]+=pv.w*pv.w;
    }
    *(float4*)&redS[h*2 + gh][4*f32] = make_float4(s4[0], s4[1], s4[2], s4[3]);
    *(float4*)&redQ[h*2 + gh][4*f32] = make_float4(q4[0], q4[1], q4[2], q4[3]);
    __syncthreads();
    if (t < 128) {
        float s = 0.f;
        #pragma unroll
        for (int j = 0; j < 8; j++) s += redS[j][t];
        p3[bid*256 + t] = s;
    } else {
        int f = t - 128;
        float qq = 0.f;
        #pragma unroll
        for (int j = 0; j < 8; j++) qq += redQ[j][f];
        p3[bid*256 + 128 + f] = qq;
    }
}

// ---------------- K6a: BN3 partial reduction (P3 has 512 rows) ----------------
__global__ __launch_bounds__(256) void k6a(const float* __restrict__ p3, float* __restrict__ r3)
{
    int j = blockIdx.x, f = threadIdx.x;
    float s = 0.f;
    for (int r = j*8; r < (j+1)*8; r++) s += p3[r*256 + f];
    r3[j*256 + f] = s;
}

// ---------------- K7: BN3-finalize + head. 1 thread/graph, 128 thr x 256 blocks ----------------
// W2h/W3h indices are wave-uniform -> scalar-cache loads (the round-9 2-lane split broke this).
__global__ __launch_bounds__(128) void k7_head(
    const float* __restrict__ pre3, const float* __restrict__ R3,
    const float* __restrict__ g3, const float* __restrict__ bt3,
    const float* __restrict__ W2h, const float* __restrict__ b2h,
    const float* __restrict__ W3h, const float* __restrict__ b3h,
    float* __restrict__ out)
{
    __shared__ float A3s[128], D3s[128];
    int t = threadIdx.x;
    {
        float s = 0.f, q = 0.f;
        for (int j = 0; j < 64; j++) { s += R3[j*256 + t]; q += R3[j*256 + 128 + t]; }
        float m = s / (float)BGR;
        float v = q / (float)BGR - m*m;
        float a = g3[t] * rsqrtf(v + EPS);
        A3s[t] = a;
        D3s[t] = bt3[t] - a*m;
    }
    __syncthreads();

    int g = blockIdx.x*128 + t;
    float accj[32];
    #pragma unroll
    for (int j = 0; j < 32; j++) accj[j] = b2h[j];
    const float* p3 = pre3 + (size_t)g*128;
    #pragma unroll 2
    for (int f4 = 0; f4 < 128; f4 += 4) {
        float4 pv = *(const float4*)(p3 + f4);
        float y0 = fmaxf(fmaf(A3s[f4+0], pv.x, D3s[f4+0]), 0.f);
        float y1 = fmaxf(fmaf(A3s[f4+1], pv.y, D3s[f4+1]), 0.f);
        float y2 = fmaxf(fmaf(A3s[f4+2], pv.z, D3s[f4+2]), 0.f);
        float y3 = fmaxf(fmaf(A3s[f4+3], pv.w, D3s[f4+3]), 0.f);
        #pragma unroll
        for (int j = 0; j < 32; j++) {
            accj[j] = fmaf(y0, W2h[(f4+0)*32+j], accj[j]);
            accj[j] = fmaf(y1, W2h[(f4+1)*32+j], accj[j]);
            accj[j] = fmaf(y2, W2h[(f4+2)*32+j], accj[j]);
            accj[j] = fmaf(y3, W2h[(f4+3)*32+j], accj[j]);
        }
    }
    float o0 = b3h[0], o1 = b3h[1];
    #pragma unroll
    for (int j = 0; j < 32; j++) {
        float yj = fmaxf(accj[j], 0.f);
        o0 = fmaf(yj, W3h[j*2+0], o0);
        o1 = fmaf(yj, W3h[j*2+1], o1);
    }
    ((float2*)out)[g] = make_float2(o0, o1);
}

extern "C" void kernel_launch(void* const* d_in, const int* in_sizes, int n_in,
                              void* d_out, int out_size, void* d_ws, size_t ws_size,
                              hipStream_t stream)
{
    (void)in_sizes; (void)n_in; (void)out_size; (void)ws_size;
    const float* x    = (const float*)d_in[0];
    const float* ew   = (const float*)d_in[1];
    const int*   eif  = (const int*)d_in[2];
    const int*   eis  = (const int*)d_in[3];
    const float* W1   = (const float*)d_in[4];
    // d_in[5] = b1: cancels exactly inside BN1 (mean subtraction) — unused
    const float* g1   = (const float*)d_in[6];
    const float* bt1  = (const float*)d_in[7];
    const float* W2   = (const float*)d_in[8];
    const float* b2   = (const float*)d_in[9];
    const float* g2   = (const float*)d_in[10];
    const float* bt2  = (const float*)d_in[11];
    const float* l1W  = (const float*)d_in[12];
    const float* l1b  = (const float*)d_in[13];
    const float* g3   = (const float*)d_in[14];
    const float* bt3  = (const float*)d_in[15];
    const float* l2W  = (const float*)d_in[16];
    const float* l2b  = (const float*)d_in[17];
    const float* l3W  = (const float*)d_in[18];
    const float* l3b  = (const float*)d_in[19];
    float* out = (float*)d_out;
    float* ws  = (float*)d_ws;

    const int* srcf = eif;  const int* dstf = eif + BGR*EF;
    const int* srcs = eis;  const int* dsts = eis + BGR*ES;

    float* U    = ws + WS_U;
    float* PRE2 = ws + WS_PRE2;
    float* PRE3 = ws + WS_PRE3;
    float* P3   = ws + WS_P3;
    float* R3   = ws + WS_R3;
    float* P1   = ws + WS_P1;
    float* R2   = ws + WS_R2;
    float* WP   = ws + WS_WP;
    float* TB   = ws + WS_TB;
    float4* TSEG= (float4*)(ws + WS_TSEG);

    k1_gcn1<<<BGR/4, 256, 0, stream>>>(x, ew, srcf, dstf, U);
    kr1<<<640, 256, 0, stream>>>(U, P1, l1W, WP);
    k2c<<<1, 256, 0, stream>>>(P1, W1, g1, bt1, W2, TB, TSEG);
    k3b<<<BGR/4, 256, 0, stream>>>(U, srcs, dsts, TB, TSEG, b2, (float2*)PRE2);
    kr2<<<640, 256, 0, stream>>>((const float2*)PRE2, R2);
    k5_lin1<<<512, 256, 0, stream>>>((const float2*)PRE2, R2, g2, bt2, WP, l1b, PRE3, P3);
    k6a<<<64, 256, 0, stream>>>(P3, R3);
    k7_head<<<256, 128, 0, stream>>>(PRE3, R3, g3, bt3, l2W, l2b, l3W, l3b, out);
}